// Round 7
// baseline (9461.810 us; speedup 1.0000x reference)
//
#include <hip/hip_runtime.h>
#include <cmath>

#define R_ROWS 1000
#define NCLS   81
#define REGW   (NCLS * 4)
#define SCORE_T 0.05f
#define NMS_T   0.5f
#define NEG_S  -1e9f
#define DETS   100
#define CLIP_V 4.135166556742356f   // log(1000/16)
#define MAXC   1000
#define SLOTS  1000                  // per-class klist region (elements)

#define NBINS   1024
#define SEL_CAP 2048
#define NBLK_CLS 80                  // classes 1..80 -> blocks 0..79
#define RPB     13                   // ceil(1000/80) stats rows per block

#define STAT_MAGIC 0xA17E57A700000000ULL
#define CLS_MAGIC  0x5A5AC3A500000000ULL
#define FLAG_MASK  0xFFFFFFFFFFFF0000ULL   // poison 0xAAAA.. fails both magics

// ---------- exact-order helpers (no FMA contraction: match numpy/XLA separate rounding) ----------

__device__ __forceinline__ float4 decode_clip(const float* __restrict__ prop,
                                              const float* __restrict__ reg,
                                              int r, int ccol, float wmax, float hmax) {
    float x1 = prop[r * 4 + 0], y1 = prop[r * 4 + 1];
    float x2 = prop[r * 4 + 2], y2 = prop[r * 4 + 3];
    float w  = __fadd_rn(__fsub_rn(x2, x1), 1.0f);
    float h  = __fadd_rn(__fsub_rn(y2, y1), 1.0f);
    float cx = __fadd_rn(x1, __fmul_rn(0.5f, w));
    float cy = __fadd_rn(y1, __fmul_rn(0.5f, h));
    const float* rr = reg + r * REGW + 4 * ccol;
    float dx = rr[0] / 10.0f;
    float dy = rr[1] / 10.0f;
    float dw = fminf(rr[2] / 5.0f, CLIP_V);
    float dh = fminf(rr[3] / 5.0f, CLIP_V);
    float pcx = __fadd_rn(__fmul_rn(dx, w), cx);
    float pcy = __fadd_rn(__fmul_rn(dy, h), cy);
    float pw  = __fmul_rn(expf(dw), w);
    float ph  = __fmul_rn(expf(dh), h);
    float ox1 = __fsub_rn(pcx, __fmul_rn(0.5f, pw));
    float oy1 = __fsub_rn(pcy, __fmul_rn(0.5f, ph));
    float ox2 = __fsub_rn(__fadd_rn(pcx, __fmul_rn(0.5f, pw)), 1.0f);
    float oy2 = __fsub_rn(__fadd_rn(pcy, __fmul_rn(0.5f, ph)), 1.0f);
    float4 o;
    o.x = fminf(fmaxf(ox1, 0.0f), wmax);
    o.y = fminf(fmaxf(oy1, 0.0f), hmax);
    o.z = fminf(fmaxf(ox2, 0.0f), wmax);
    o.w = fminf(fmaxf(oy2, 0.0f), hmax);
    return o;
}

__device__ __forceinline__ float iou_legacy(float ax1, float ay1, float ax2, float ay2,
                                            float bx1, float by1, float bx2, float by2) {
    float aw = __fadd_rn(__fsub_rn(ax2, ax1), 1.0f);
    float ah = __fadd_rn(__fsub_rn(ay2, ay1), 1.0f);
    float areaA = __fmul_rn(aw, ah);
    float bw = __fadd_rn(__fsub_rn(bx2, bx1), 1.0f);
    float bh = __fadd_rn(__fsub_rn(by2, by1), 1.0f);
    float areaB = __fmul_rn(bw, bh);
    float ltx = fmaxf(ax1, bx1), lty = fmaxf(ay1, by1);
    float rbx = fminf(ax2, bx2), rby = fminf(ay2, by2);
    float wx = fmaxf(__fadd_rn(__fsub_rn(rbx, ltx), 1.0f), 0.0f);
    float wy = fmaxf(__fadd_rn(__fsub_rn(rby, lty), 1.0f), 0.0f);
    float inter = __fmul_rn(wx, wy);
    float denom = __fsub_rn(__fadd_rn(areaA, areaB), inter);
    return inter / denom;
}

// monotone coarse bin of a positive float score (positive IEEE bits are order-preserving)
__device__ __forceinline__ int bin_of(float s) {
    int idx = (int)(__float_as_uint(s) >> 16) - 0x3D00;   // scores in (0.05,1] -> [76,640]
    return idx < 0 ? 0 : (idx > NBINS - 1 ? NBINS - 1 : idx);
}

__device__ __forceinline__ unsigned long long key_of(float s, unsigned f) {
    // (score desc, flat asc) as one monotone u64; valid keys nonzero (score > 0.05)
    return ((unsigned long long)__float_as_uint(s) << 32) | (unsigned long long)(~f);
}
__device__ __forceinline__ float key_score(unsigned long long k) {
    return __uint_as_float((unsigned)(k >> 32));
}
__device__ __forceinline__ int key_flat(unsigned long long k) {
    return (int)(~(unsigned)k);
}

// device-scope (sc1) coherent accesses — per-access coherence, no L2 wbl2/inv fences
__device__ __forceinline__ void dev_store_u64(unsigned long long* p, unsigned long long v) {
    __hip_atomic_store(p, v, __ATOMIC_RELAXED, __HIP_MEMORY_SCOPE_AGENT);
}
__device__ __forceinline__ unsigned long long dev_load_u64(const unsigned long long* p) {
    return __hip_atomic_load(p, __ATOMIC_RELAXED, __HIP_MEMORY_SCOPE_AGENT);
}
__device__ __forceinline__ void dev_store_f32(float* p, float v) {
    __hip_atomic_store(p, v, __ATOMIC_RELAXED, __HIP_MEMORY_SCOPE_AGENT);
}
__device__ __forceinline__ float dev_load_f32(const float* p) {
    return __hip_atomic_load(p, __ATOMIC_RELAXED, __HIP_MEMORY_SCOPE_AGENT);
}

// upper-bound search: returns c with koff[c] <= g < koff[c+1]
__device__ __forceinline__ int find_class(const int* koff, int g) {
    int lo = 0, hi = NBLK_CLS;
    while (hi - lo > 1) { int mid = (lo + hi) >> 1; if (g >= koff[mid]) lo = mid; else hi = mid; }
    return lo;
}

// ---------- single kernel: 80 class blocks; partitioned stats; block 0 selects ----------

__global__ __launch_bounds__(256) void k_all(const float* __restrict__ logits,
                                             const float* __restrict__ reg,
                                             const float* __restrict__ prop,
                                             const int* __restrict__ piw,
                                             const int* __restrict__ pih,
                                             unsigned long long* __restrict__ sflags,
                                             unsigned long long* __restrict__ cflags,
                                             float* __restrict__ rowmax_g,
                                             float* __restrict__ rowsum_g,
                                             unsigned long long* __restrict__ klist,
                                             float* __restrict__ out) {
    __shared__ float rowmax_s[R_ROWS];
    __shared__ float rowsum_s[R_ROWS];
    __shared__ float us[MAXC];  __shared__ int uidx[MAXC];
    __shared__ float ss[MAXC];  __shared__ int sidx[MAXC];
    __shared__ float bx4[MAXC][4];
    __shared__ int   supp[MAXC];
    __shared__ int   cnt, sh_kept;
    // selector-phase
    __shared__ int   koff[NBLK_CLS + 1];
    __shared__ int   cs[256];
    __shared__ int   hist_s[NBINS];
    __shared__ unsigned long long ck[SEL_CAP + 4];
    __shared__ float sel_s[DETS]; __shared__ int sel_f[DETS];
    __shared__ int   sh_cut;

    const int cidx = blockIdx.x;       // 0..79
    const int ccol = cidx + 1;         // skip background class 0
    const int t    = threadIdx.x;
    const int lane = t & 63;
    const int wv   = t >> 6;
    const float wmax = (float)(*piw - 1);
    const float hmax = (float)(*pih - 1);

    if (t == 0) cnt = 0;

    // ---- Phase 0a: coalesced softmax stats for MY 13 rows (bit-identical to old kernel A) ----
    {
        int r0 = cidx * RPB;
        int r1 = r0 + RPB; if (r1 > R_ROWS) r1 = R_ROWS;
        for (int r = r0 + wv; r < r1; r += 4) {
            float v1 = logits[r * NCLS + lane];
            float v2 = (lane < NCLS - 64) ? logits[r * NCLS + 64 + lane] : -INFINITY;
            float m = fmaxf(v1, v2);
            #pragma unroll
            for (int off = 32; off; off >>= 1) m = fmaxf(m, __shfl_xor(m, off));
            float s = expf(__fsub_rn(v1, m));
            if (lane < NCLS - 64) s = __fadd_rn(s, expf(__fsub_rn(v2, m)));
            #pragma unroll
            for (int off = 32; off; off >>= 1) s = __fadd_rn(s, __shfl_xor(s, off));
            if (lane == 0) { dev_store_f32(&rowmax_g[r], m); dev_store_f32(&rowsum_g[r], s); }
        }
    }
    __syncthreads();   // drains vmcnt(0): stat stores at coherence point
    if (t == 0) dev_store_u64(&sflags[cidx], STAT_MAGIC | (unsigned long long)cidx);

    // ---- Phase 0b: poll all stats flags, coalesced-load stats to LDS ----
    // Stale flags from prior replay are benign: stats are deterministic -> bit-identical.
    if (t < NBLK_CLS) {
        while ((dev_load_u64(&sflags[t]) & FLAG_MASK) != STAT_MAGIC)
            __builtin_amdgcn_s_sleep(2);
    }
    __syncthreads();
    for (int r = t; r < R_ROWS; r += 256) {
        rowmax_s[r] = dev_load_f32(&rowmax_g[r]);
        rowsum_s[r] = dev_load_f32(&rowsum_g[r]);
    }
    __syncthreads();

    // ---- Phase 1: valid candidates (score > thresh), unsorted compaction into LDS ----
    for (int r = t; r < R_ROWS; r += 256) {
        float z = logits[r * NCLS + ccol];
        float s = expf(__fsub_rn(z, rowmax_s[r])) / rowsum_s[r];
        if (s > SCORE_T) {
            int p = atomicAdd(&cnt, 1);
            us[p] = s; uidx[p] = r;
        }
    }
    __syncthreads();
    const int M = cnt;

    // ---- Phase 2a: exact rank sort (score desc, row asc) ----
    for (int i = t; i < M; i += 256) {
        float si = us[i]; int ri = uidx[i];
        int rank = 0;
        for (int j = 0; j < M; j++) {
            float sj = us[j]; int rj = uidx[j];
            rank += (sj > si) || (sj == si && rj < ri);
        }
        ss[rank] = si; sidx[rank] = ri;
    }
    __syncthreads();
    // ---- Phase 2b: decode + clip ----
    for (int i = t; i < M; i += 256) {
        float4 b = decode_clip(prop, reg, sidx[i], ccol, wmax, hmax);
        bx4[i][0] = b.x; bx4[i][1] = b.y; bx4[i][2] = b.z; bx4[i][3] = b.w;
        supp[i] = 0;
    }
    __syncthreads();

    // ---- Phase 3+4: NMS + compact append to per-class slots ----
    if (M <= 64) {
        // wave-ballot NMS: zero barriers, zero LDS traffic (block-uniform branch)
        if (wv == 0) {
            const bool valid = lane < M;
            float b0 = 0, b1 = 0, b2 = 0, b3 = 0, sc = 0; int ri = 0;
            if (valid) { b0 = bx4[lane][0]; b1 = bx4[lane][1]; b2 = bx4[lane][2]; b3 = bx4[lane][3];
                         sc = ss[lane]; ri = sidx[lane]; }
            unsigned long long suppm = 0;
            for (int i = 0; i < M; ++i) {
                if ((suppm >> i) & 1ULL) continue;          // wave-uniform
                float ax1 = __shfl(b0, i), ay1 = __shfl(b1, i);
                float ax2 = __shfl(b2, i), ay2 = __shfl(b3, i);
                bool kill = valid && (lane > i) &&
                            (iou_legacy(ax1, ay1, ax2, ay2, b0, b1, b2, b3) > NMS_T);
                suppm |= __ballot(kill);
            }
            unsigned long long keepm = ~suppm;
            if (M < 64) keepm &= (1ULL << M) - 1ULL;
            if (valid && ((keepm >> lane) & 1ULL)) {
                int pos = __popcll(keepm & ((1ULL << lane) - 1ULL));
                dev_store_u64(&klist[(size_t)cidx * SLOTS + pos],
                              key_of(sc, (unsigned)(cidx * R_ROWS + ri)));
            }
            if (lane == 0) sh_kept = __popcll(keepm);
        }
    } else {
        // fallback: sequential-i LDS NMS (block-uniform branch, barriers legal)
        for (int i = 0; i < M; i++) {
            if (!supp[i]) {
                float ax1 = bx4[i][0], ay1 = bx4[i][1], ax2 = bx4[i][2], ay2 = bx4[i][3];
                for (int j = i + 1 + t; j < M; j += 256) {
                    if (!supp[j]) {
                        float v = iou_legacy(ax1, ay1, ax2, ay2,
                                             bx4[j][0], bx4[j][1], bx4[j][2], bx4[j][3]);
                        if (v > NMS_T) supp[j] = 1;
                    }
                }
            }
            __syncthreads();
        }
        for (int i = t; i < M; i += 256) {
            if (!supp[i]) {
                int pos = 0;
                for (int j = 0; j < i; ++j) pos += !supp[j];
                dev_store_u64(&klist[(size_t)cidx * SLOTS + pos],
                              key_of(ss[i], (unsigned)(cidx * R_ROWS + sidx[i])));
            }
        }
        if (t == 0) {
            int kc = 0;
            for (int i = 0; i < M; ++i) kc += !supp[i];
            sh_kept = kc;
        }
    }
    __syncthreads();   // drains vmcnt(0): klist stores at coherence point; sh_kept visible
    if (t == 0) dev_store_u64(&cflags[cidx], CLS_MAGIC | (unsigned long long)sh_kept);

    if (cidx != 0) return;

    // ================= selector (block 0) =================
    // Stale cflags/klist from prior replay are bit-identical (deterministic) -> benign.
    if (t < NBLK_CLS) {
        unsigned long long v;
        for (;;) {
            v = dev_load_u64(&cflags[t]);
            if ((v & FLAG_MASK) == CLS_MAGIC) break;
            __builtin_amdgcn_s_sleep(2);
        }
        cs[t] = (int)(v & 0xFFFFULL);            // per-class kept count
    }
    for (int b = t; b < NBINS; b += 256) hist_s[b] = 0;
    __syncthreads();
    if (t == 0) {
        int acc = 0;
        for (int c = 0; c < NBLK_CLS; ++c) { koff[c] = acc; acc += cs[c]; }
        koff[NBLK_CLS] = acc;
        sh_cut = 0;
    }
    __syncthreads();
    const int K = koff[NBLK_CLS];                // total kept (all keys valid)
    const int target = (K < DETS) ? K : DETS;

    if (K <= SEL_CAP) {
        // one sc1 sweep: keys -> LDS, histogram in LDS
        for (int g = t; g < K; g += 256) {
            int c = find_class(koff, g);
            unsigned long long k = dev_load_u64(&klist[(size_t)c * SLOTS + (g - koff[c])]);
            ck[g] = k;
            atomicAdd(&hist_s[bin_of(key_score(k))], 1);
        }
        __syncthreads();

        // suffix scan of 1024 bins: S[b] = #keys with bin >= b
        int v0 = hist_s[4 * t], v1 = hist_s[4 * t + 1], v2 = hist_s[4 * t + 2], v3 = hist_s[4 * t + 3];
        int s3 = v3, s2 = v2 + s3, s1 = v1 + s2, s0 = v0 + s1;
        cs[t] = s0;
        __syncthreads();
        for (int off = 1; off < 256; off <<= 1) {
            int x = cs[t] + ((t + off < 256) ? cs[t + off] : 0);
            __syncthreads();
            cs[t] = x;
            __syncthreads();
        }
        int tail = (t < 255) ? cs[t + 1] : 0;
        int S0 = s0 + tail, S1 = s1 + tail, S2 = s2 + tail, S3 = s3 + tail;
        if (target > 0) {
            int best = -1;
            if      (S3 >= target) best = 4 * t + 3;
            else if (S2 >= target) best = 4 * t + 2;
            else if (S1 >= target) best = 4 * t + 1;
            else if (S0 >= target) best = 4 * t;
            if (best >= 0) atomicMax(&sh_cut, best);
        }
        __syncthreads();
        const int cut = sh_cut;        // survivors (bin>=cut) ⊇ top-target, count small

        int Kp = (K + 3) & ~3;
        if (t < Kp - K) ck[K + t] = 0; // pad: key 0 never outranks a real key
        __syncthreads();
        for (int g = t; g < K; g += 256) {
            unsigned long long ki = ck[g];
            if (bin_of(key_score(ki)) < cut) continue;
            int r = 0;
            for (int j = 0; j < Kp; j += 4)
                r += (int)(ck[j] > ki) + (int)(ck[j + 1] > ki)
                   + (int)(ck[j + 2] > ki) + (int)(ck[j + 3] > ki);
            if (r < DETS) {
                sel_s[r] = key_score(ki);
                sel_f[r] = key_flat(ki);
            }
        }
    } else {
        // safe fallback (degenerate flood): exact rank via global sweeps
        for (int g = t; g < K; g += 256) {
            int c = find_class(koff, g);
            unsigned long long ki = dev_load_u64(&klist[(size_t)c * SLOTS + (g - koff[c])]);
            int r = 0;
            for (int g2 = 0; g2 < K; ++g2) {
                int c2 = find_class(koff, g2);
                r += (int)(dev_load_u64(&klist[(size_t)c2 * SLOTS + (g2 - koff[c2])]) > ki);
            }
            if (r < DETS) {
                sel_s[r] = key_score(ki);
                sel_f[r] = key_flat(ki);
            }
        }
    }
    __syncthreads();

    // tail-fill (only when K < 100; then ck[0..K) holds ALL kept keys since cut keeps all)
    if (t == 0 && target < DETS) {
        int n = target, f = 0;
        while (n < DETS) {
            bool used = false;
            for (int q = 0; q < K; q++) if (key_flat(ck[q]) == f) { used = true; break; }
            if (!used) { sel_s[n] = NEG_S; sel_f[n] = f; n++; }
            f++;
        }
    }
    __syncthreads();

    // decode + write 600 outputs
    if (t < DETS) {
        int f = sel_f[t];
        int c2 = f / R_ROWS;
        int r  = f % R_ROWS;
        float4 b = decode_clip(prop, reg, r, c2 + 1, wmax, hmax);
        out[t] = sel_s[t];
        out[DETS + 4 * t + 0] = b.x;
        out[DETS + 4 * t + 1] = b.y;
        out[DETS + 4 * t + 2] = b.z;
        out[DETS + 4 * t + 3] = b.w;
        out[DETS * 5 + t] = (float)(c2 + 1);
    }
}

// ---------- host launcher ----------

extern "C" void kernel_launch(void* const* d_in, const int* in_sizes, int n_in,
                              void* d_out, int out_size, void* d_ws, size_t ws_size,
                              hipStream_t stream) {
    (void)in_sizes; (void)n_in; (void)out_size; (void)ws_size;
    const float* logits = (const float*)d_in[0];
    const float* reg    = (const float*)d_in[1];
    const float* prop   = (const float*)d_in[2];
    const int*   piw    = (const int*)d_in[3];
    const int*   pih    = (const int*)d_in[4];
    float* out = (float*)d_out;

    // workspace (bytes): sflags[80]@0, cflags[80]@1024, rowmax[1000]@2048,
    // rowsum[1000]@6144, klist[80*1000 u64]@12288 (total ~652 KB; ws is 256 MB).
    // NO zero-init needed: 48-bit magic flags reject 0xAA poison; replay-stale
    // values are bit-identical to current-replay values (full determinism).
    char* ws = (char*)d_ws;
    unsigned long long* sflags = (unsigned long long*)(ws);
    unsigned long long* cflags = (unsigned long long*)(ws + 1024);
    float* rowmax_g = (float*)(ws + 2048);
    float* rowsum_g = (float*)(ws + 6144);
    unsigned long long* klist = (unsigned long long*)(ws + 12288);

    k_all<<<dim3(NBLK_CLS), dim3(256), 0, stream>>>(logits, reg, prop, piw, pih,
                                                    sflags, cflags, rowmax_g, rowsum_g,
                                                    klist, out);
}

// Round 8
// 181.430 us; speedup vs baseline: 52.1513x; 52.1513x over previous
//
#include <hip/hip_runtime.h>
#include <cmath>

#define R_ROWS 1000
#define NCLS   81
#define REGW   (NCLS * 4)
#define SCORE_T 0.05f
#define NMS_T   0.5f
#define NEG_S  -1e9f
#define DETS   100
#define CLIP_V 4.135166556742356f   // log(1000/16)
#define MAXC   1000

#define NBINS   1024
#define SEL_CAP 2048
#define CAP_DEFAULT 20000
#define NBLK_CLS 80                  // classes 1..80 -> blocks 0..79

// ---------- exact-order helpers (no FMA contraction: match numpy/XLA separate rounding) ----------

__device__ __forceinline__ float4 decode_clip(const float* __restrict__ prop,
                                              const float* __restrict__ reg,
                                              int r, int ccol, float wmax, float hmax) {
    float x1 = prop[r * 4 + 0], y1 = prop[r * 4 + 1];
    float x2 = prop[r * 4 + 2], y2 = prop[r * 4 + 3];
    float w  = __fadd_rn(__fsub_rn(x2, x1), 1.0f);
    float h  = __fadd_rn(__fsub_rn(y2, y1), 1.0f);
    float cx = __fadd_rn(x1, __fmul_rn(0.5f, w));
    float cy = __fadd_rn(y1, __fmul_rn(0.5f, h));
    const float* rr = reg + r * REGW + 4 * ccol;
    float dx = rr[0] / 10.0f;
    float dy = rr[1] / 10.0f;
    float dw = fminf(rr[2] / 5.0f, CLIP_V);
    float dh = fminf(rr[3] / 5.0f, CLIP_V);
    float pcx = __fadd_rn(__fmul_rn(dx, w), cx);
    float pcy = __fadd_rn(__fmul_rn(dy, h), cy);
    float pw  = __fmul_rn(expf(dw), w);
    float ph  = __fmul_rn(expf(dh), h);
    float ox1 = __fsub_rn(pcx, __fmul_rn(0.5f, pw));
    float oy1 = __fsub_rn(pcy, __fmul_rn(0.5f, ph));
    float ox2 = __fsub_rn(__fadd_rn(pcx, __fmul_rn(0.5f, pw)), 1.0f);
    float oy2 = __fsub_rn(__fadd_rn(pcy, __fmul_rn(0.5f, ph)), 1.0f);
    float4 o;
    o.x = fminf(fmaxf(ox1, 0.0f), wmax);
    o.y = fminf(fmaxf(oy1, 0.0f), hmax);
    o.z = fminf(fmaxf(ox2, 0.0f), wmax);
    o.w = fminf(fmaxf(oy2, 0.0f), hmax);
    return o;
}

__device__ __forceinline__ float iou_legacy(float ax1, float ay1, float ax2, float ay2,
                                            float bx1, float by1, float bx2, float by2) {
    float aw = __fadd_rn(__fsub_rn(ax2, ax1), 1.0f);
    float ah = __fadd_rn(__fsub_rn(ay2, ay1), 1.0f);
    float areaA = __fmul_rn(aw, ah);
    float bw = __fadd_rn(__fsub_rn(bx2, bx1), 1.0f);
    float bh = __fadd_rn(__fsub_rn(by2, by1), 1.0f);
    float areaB = __fmul_rn(bw, bh);
    float ltx = fmaxf(ax1, bx1), lty = fmaxf(ay1, by1);
    float rbx = fminf(ax2, bx2), rby = fminf(ay2, by2);
    float wx = fmaxf(__fadd_rn(__fsub_rn(rbx, ltx), 1.0f), 0.0f);
    float wy = fmaxf(__fadd_rn(__fsub_rn(rby, lty), 1.0f), 0.0f);
    float inter = __fmul_rn(wx, wy);
    float denom = __fsub_rn(__fadd_rn(areaA, areaB), inter);
    return inter / denom;
}

// monotone coarse bin of a positive float score (positive IEEE bits are order-preserving)
__device__ __forceinline__ int bin_of(float s) {
    int idx = (int)(__float_as_uint(s) >> 16) - 0x3D00;   // scores in (0.05,1] -> [76,640]
    return idx < 0 ? 0 : (idx > NBINS - 1 ? NBINS - 1 : idx);
}

__device__ __forceinline__ unsigned long long key_of(float s, unsigned f) {
    // (score desc, flat asc) as one monotone u64; valid keys nonzero (score > 0.05)
    return ((unsigned long long)__float_as_uint(s) << 32) | (unsigned long long)(~f);
}
__device__ __forceinline__ float key_score(unsigned long long k) {
    return __uint_as_float((unsigned)(k >> 32));
}
__device__ __forceinline__ int key_flat(unsigned long long k) {
    return (int)(~(unsigned)k);
}

// device-scope (sc1) coherent accesses — per-access coherence, no L2 wbl2/inv fences.
// NOTE (R7 lesson): these are safe for one-shot producer->consumer data reads after an
// RMW handoff, but NEVER spin-poll on them — stale local-L2 lines are not invalidated
// by remote plain stores. All cross-block signaling below is atomic-RMW based.
__device__ __forceinline__ void dev_store_u64(unsigned long long* p, unsigned long long v) {
    __hip_atomic_store(p, v, __ATOMIC_RELAXED, __HIP_MEMORY_SCOPE_AGENT);
}
__device__ __forceinline__ unsigned long long dev_load_u64(const unsigned long long* p) {
    return __hip_atomic_load(p, __ATOMIC_RELAXED, __HIP_MEMORY_SCOPE_AGENT);
}

// ---------- single kernel: 80 class blocks; last-finishing block runs selection ----------

__global__ __launch_bounds__(256) void k_all(const float* __restrict__ logits,
                                             const float* __restrict__ reg,
                                             const float* __restrict__ prop,
                                             const int* __restrict__ piw,
                                             const int* __restrict__ pih,
                                             int* __restrict__ gcount,
                                             int* __restrict__ done,
                                             unsigned long long* __restrict__ klist,
                                             int cap,
                                             float* __restrict__ out) {
    __shared__ float rowmax_s[R_ROWS];
    __shared__ float rowsum_s[R_ROWS];
    __shared__ float us[MAXC];  __shared__ int uidx[MAXC];
    __shared__ float ss[MAXC];  __shared__ int sidx[MAXC];
    __shared__ float bx4[MAXC][4];
    __shared__ int   supp[MAXC];
    __shared__ int   cnt, sh_base, sh_last;
    // selector-phase
    __shared__ int   cs[256];
    __shared__ int   hist_s[NBINS];
    __shared__ unsigned long long ck[SEL_CAP + 4];
    __shared__ float sel_s[DETS]; __shared__ int sel_f[DETS];
    __shared__ int   sh_cut, sh_mcnt;

    const int cidx = blockIdx.x;       // 0..79
    const int ccol = cidx + 1;         // skip background class 0
    const int t    = threadIdx.x;
    const int lane = t & 63;
    const int wv   = t >> 6;
    const float wmax = (float)(*piw - 1);
    const float hmax = (float)(*pih - 1);

    if (t == 0) cnt = 0;

    // ---- Phase 0: ALL 1000 rows' softmax stats, computed in-block (no communication).
    // Wave-per-row, lane-per-class: coalesced, bit-identical to the proven kernel-A
    // reduction. Redundant x80 across blocks but fully parallel (~2-3 us).
    for (int r = wv; r < R_ROWS; r += 4) {
        float v1 = logits[r * NCLS + lane];
        float v2 = (lane < NCLS - 64) ? logits[r * NCLS + 64 + lane] : -INFINITY;
        float m = fmaxf(v1, v2);
        #pragma unroll
        for (int off = 32; off; off >>= 1) m = fmaxf(m, __shfl_xor(m, off));
        float s = expf(__fsub_rn(v1, m));
        if (lane < NCLS - 64) s = __fadd_rn(s, expf(__fsub_rn(v2, m)));
        #pragma unroll
        for (int off = 32; off; off >>= 1) s = __fadd_rn(s, __shfl_xor(s, off));
        if (lane == 0) { rowmax_s[r] = m; rowsum_s[r] = s; }
    }
    __syncthreads();

    // ---- Phase 1: valid candidates (score > thresh), unsorted compaction into LDS ----
    for (int r = t; r < R_ROWS; r += 256) {
        float z = logits[r * NCLS + ccol];
        float s = expf(__fsub_rn(z, rowmax_s[r])) / rowsum_s[r];
        if (s > SCORE_T) {
            int p = atomicAdd(&cnt, 1);
            us[p] = s; uidx[p] = r;
        }
    }
    __syncthreads();
    const int M = cnt;

    // ---- Phase 2a: exact rank sort (score desc, row asc) ----
    for (int i = t; i < M; i += 256) {
        float si = us[i]; int ri = uidx[i];
        int rank = 0;
        for (int j = 0; j < M; j++) {
            float sj = us[j]; int rj = uidx[j];
            rank += (sj > si) || (sj == si && rj < ri);
        }
        ss[rank] = si; sidx[rank] = ri;
    }
    __syncthreads();
    // ---- Phase 2b: decode + clip ----
    for (int i = t; i < M; i += 256) {
        float4 b = decode_clip(prop, reg, sidx[i], ccol, wmax, hmax);
        bx4[i][0] = b.x; bx4[i][1] = b.y; bx4[i][2] = b.z; bx4[i][3] = b.w;
        supp[i] = 0;
    }
    __syncthreads();

    // ---- Phase 3+4: NMS + append kept keys (positions via device atomicAdd RMW) ----
    if (M <= 64) {
        // wave-ballot NMS on wave 0: zero barriers, zero LDS traffic
        if (wv == 0) {
            const bool valid = lane < M;
            float b0 = 0, b1 = 0, b2 = 0, b3 = 0, sc = 0; int ri = 0;
            if (valid) { b0 = bx4[lane][0]; b1 = bx4[lane][1]; b2 = bx4[lane][2]; b3 = bx4[lane][3];
                         sc = ss[lane]; ri = sidx[lane]; }
            unsigned long long suppm = 0;
            for (int i = 0; i < M; ++i) {
                if ((suppm >> i) & 1ULL) continue;          // wave-uniform
                float ax1 = __shfl(b0, i), ay1 = __shfl(b1, i);
                float ax2 = __shfl(b2, i), ay2 = __shfl(b3, i);
                bool kill = valid && (lane > i) &&
                            (iou_legacy(ax1, ay1, ax2, ay2, b0, b1, b2, b3) > NMS_T);
                suppm |= __ballot(kill);
            }
            unsigned long long keepm = ~suppm;
            if (M < 64) keepm &= (1ULL << M) - 1ULL;
            int nk = __popcll(keepm);
            int base = 0;
            if (lane == 0 && nk > 0) base = atomicAdd(gcount, nk);
            base = __shfl(base, 0);
            if (valid && ((keepm >> lane) & 1ULL)) {
                int pos = __popcll(keepm & ((1ULL << lane) - 1ULL));
                int p = base + pos;
                if (p < cap)
                    dev_store_u64(&klist[p], key_of(sc, (unsigned)(cidx * R_ROWS + ri)));
            }
        }
    } else {
        // fallback: sequential-i LDS NMS (block-uniform branch, barriers legal)
        for (int i = 0; i < M; i++) {
            if (!supp[i]) {
                float ax1 = bx4[i][0], ay1 = bx4[i][1], ax2 = bx4[i][2], ay2 = bx4[i][3];
                for (int j = i + 1 + t; j < M; j += 256) {
                    if (!supp[j]) {
                        float v = iou_legacy(ax1, ay1, ax2, ay2,
                                             bx4[j][0], bx4[j][1], bx4[j][2], bx4[j][3]);
                        if (v > NMS_T) supp[j] = 1;
                    }
                }
            }
            __syncthreads();
        }
        if (t == 0) {
            int kc = 0;
            for (int i = 0; i < M; ++i) kc += !supp[i];
            sh_base = (kc > 0) ? atomicAdd(gcount, kc) : 0;
        }
        __syncthreads();
        for (int i = t; i < M; i += 256) {
            if (!supp[i]) {
                int pos = 0;
                for (int j = 0; j < i; ++j) pos += !supp[j];
                int p = sh_base + pos;
                if (p < cap)
                    dev_store_u64(&klist[p], key_of(ss[i], (unsigned)(cidx * R_ROWS + sidx[i])));
            }
        }
    }

    // ---- last-block-done handoff (RMW only — R7 lesson: never poll plain stores) ----
    __syncthreads();   // drains vmcnt(0): all sc1 stores at coherence point
    if (t == 0) sh_last = (atomicAdd(done, 1) == NBLK_CLS - 1) ? 1 : 0;
    __syncthreads();
    if (!sh_last) return;

    // ================= selector (exactly one block: the last to finish) =================
    int K = atomicAdd(gcount, 0);      // RMW read: always fresh at coherence point
    if (K > cap) K = cap;
    const int target = (K < DETS) ? K : DETS;

    for (int b = t; b < NBINS; b += 256) hist_s[b] = 0;
    if (t == 0) { sh_cut = 0; sh_mcnt = 0; }
    __syncthreads();

    // pass 1: histogram all kept keys (sc1 loads; lines not in local L2 except our own)
    for (int g = t; g < K; g += 256) {
        unsigned long long k = dev_load_u64(&klist[g]);
        atomicAdd(&hist_s[bin_of(key_score(k))], 1);
    }
    __syncthreads();

    // suffix scan of 1024 bins: S[b] = #keys with bin >= b
    int v0 = hist_s[4 * t], v1 = hist_s[4 * t + 1], v2 = hist_s[4 * t + 2], v3 = hist_s[4 * t + 3];
    int s3 = v3, s2 = v2 + s3, s1 = v1 + s2, s0 = v0 + s1;
    cs[t] = s0;
    __syncthreads();
    for (int off = 1; off < 256; off <<= 1) {
        int x = cs[t] + ((t + off < 256) ? cs[t + off] : 0);
        __syncthreads();
        cs[t] = x;
        __syncthreads();
    }
    int tail = (t < 255) ? cs[t + 1] : 0;
    int S0 = s0 + tail, S1 = s1 + tail, S2 = s2 + tail, S3 = s3 + tail;
    if (target > 0) {
        int best = -1;
        if      (S3 >= target) best = 4 * t + 3;
        else if (S2 >= target) best = 4 * t + 2;
        else if (S1 >= target) best = 4 * t + 1;
        else if (S0 >= target) best = 4 * t;
        if (best >= 0) atomicMax(&sh_cut, best);
    }
    __syncthreads();
    const int cut = sh_cut;   // survivors (bin >= cut) ⊇ top-target; survivor count small

    // pass 2: compact survivors into LDS
    for (int g = t; g < K; g += 256) {
        unsigned long long k = dev_load_u64(&klist[g]);
        if (bin_of(key_score(k)) >= cut) {
            int p = atomicAdd(&sh_mcnt, 1);
            if (p < SEL_CAP) ck[p] = k;
        }
    }
    __syncthreads();
    const int Mc = sh_mcnt;

    if (Mc <= SEL_CAP) {
        // exact rank among survivors (== global ranks; bijective -> direct scatter)
        int Mp = (Mc + 3) & ~3;
        if (t < Mp - Mc) ck[Mc + t] = 0;   // pad: key 0 never outranks a real key
        __syncthreads();
        for (int i = t; i < Mc; i += 256) {
            unsigned long long ki = ck[i];
            int r = 0;
            for (int j = 0; j < Mp; j += 4)
                r += (int)(ck[j] > ki) + (int)(ck[j + 1] > ki)
                   + (int)(ck[j + 2] > ki) + (int)(ck[j + 3] > ki);
            if (r < DETS) {
                sel_s[r] = key_score(ki);
                sel_f[r] = key_flat(ki);
            }
        }
    } else {
        // safe fallback (degenerate tie flood): exact rank vs full global list
        for (int g = t; g < K; g += 256) {
            unsigned long long ki = dev_load_u64(&klist[g]);
            if (bin_of(key_score(ki)) < cut) continue;
            int r = 0;
            for (int j = 0; j < K; j++)
                r += (int)(dev_load_u64(&klist[j]) > ki);
            if (r < DETS) {
                sel_s[r] = key_score(ki);
                sel_f[r] = key_flat(ki);
            }
        }
    }
    __syncthreads();

    // tail-fill (only when K < 100; then cut==0 so ck[0..Mc)==all kept keys)
    if (t == 0 && target < DETS) {
        int n = target, f = 0;
        while (n < DETS) {
            bool used = false;
            for (int q = 0; q < Mc; q++) if (key_flat(ck[q]) == f) { used = true; break; }
            if (!used) { sel_s[n] = NEG_S; sel_f[n] = f; n++; }
            f++;
        }
    }
    __syncthreads();

    // decode + write 600 outputs
    if (t < DETS) {
        int f = sel_f[t];
        int c2 = f / R_ROWS;
        int r  = f % R_ROWS;
        float4 b = decode_clip(prop, reg, r, c2 + 1, wmax, hmax);
        out[t] = sel_s[t];
        out[DETS + 4 * t + 0] = b.x;
        out[DETS + 4 * t + 1] = b.y;
        out[DETS + 4 * t + 2] = b.z;
        out[DETS + 4 * t + 3] = b.w;
        out[DETS * 5 + t] = (float)(c2 + 1);
    }
}

// ---------- host launcher ----------

extern "C" void kernel_launch(void* const* d_in, const int* in_sizes, int n_in,
                              void* d_out, int out_size, void* d_ws, size_t ws_size,
                              hipStream_t stream) {
    (void)in_sizes; (void)n_in; (void)out_size;
    const float* logits = (const float*)d_in[0];
    const float* reg    = (const float*)d_in[1];
    const float* prop   = (const float*)d_in[2];
    const int*   piw    = (const int*)d_in[3];
    const int*   pih    = (const int*)d_in[4];
    float* out = (float*)d_out;

    // workspace (bytes): gcount@0, done@4, klist[cap] u64 @4096.
    // gcount/done must be zero at kernel start on EVERY call -> 8-byte async memset
    // (graph-capturable). klist needs no init: entries beyond gcount never read.
    char* ws = (char*)d_ws;
    int* gcount = (int*)(ws);
    int* done   = (int*)(ws + 4);
    unsigned long long* klist = (unsigned long long*)(ws + 4096);

    long avail = (long)ws_size - 4096;
    int cap = CAP_DEFAULT;
    if (avail < (long)cap * 8) cap = (int)(avail / 8);
    if (cap < 1) cap = 1;

    hipMemsetAsync(ws, 0, 8, stream);
    k_all<<<dim3(NBLK_CLS), dim3(256), 0, stream>>>(logits, reg, prop, piw, pih,
                                                    gcount, done, klist, cap, out);
}

// Round 9
// 38.322 us; speedup vs baseline: 246.9039x; 4.7344x over previous
//
#include <hip/hip_runtime.h>
#include <cmath>

#define R_ROWS 1000
#define NCLS   81
#define REGW   (NCLS * 4)
#define SCORE_T 0.05f
#define NMS_T   0.5f
#define NEG_S  -1e9f
#define DETS   100
#define CLIP_V 4.135166556742356f   // log(1000/16)
#define MAXC   1000
#define SLOTS  1000                  // per-class klist region
#define NBLK_CLS 80                  // classes 1..80 -> blocks 0..79

#define NBINS    1024
#define CK_CAP   2560                // LDS key buffer (typ. K ~ 2000)
#define SURV_CAP 512                 // LDS survivor buffer (typ. Mc ~ 150)

// ---------- exact-order helpers (no FMA contraction: match numpy/XLA separate rounding) ----------

__device__ __forceinline__ float4 decode_clip(const float* __restrict__ prop,
                                              const float* __restrict__ reg,
                                              int r, int ccol, float wmax, float hmax) {
    float x1 = prop[r * 4 + 0], y1 = prop[r * 4 + 1];
    float x2 = prop[r * 4 + 2], y2 = prop[r * 4 + 3];
    float w  = __fadd_rn(__fsub_rn(x2, x1), 1.0f);
    float h  = __fadd_rn(__fsub_rn(y2, y1), 1.0f);
    float cx = __fadd_rn(x1, __fmul_rn(0.5f, w));
    float cy = __fadd_rn(y1, __fmul_rn(0.5f, h));
    const float* rr = reg + r * REGW + 4 * ccol;
    float dx = rr[0] / 10.0f;
    float dy = rr[1] / 10.0f;
    float dw = fminf(rr[2] / 5.0f, CLIP_V);
    float dh = fminf(rr[3] / 5.0f, CLIP_V);
    float pcx = __fadd_rn(__fmul_rn(dx, w), cx);
    float pcy = __fadd_rn(__fmul_rn(dy, h), cy);
    float pw  = __fmul_rn(expf(dw), w);
    float ph  = __fmul_rn(expf(dh), h);
    float ox1 = __fsub_rn(pcx, __fmul_rn(0.5f, pw));
    float oy1 = __fsub_rn(pcy, __fmul_rn(0.5f, ph));
    float ox2 = __fsub_rn(__fadd_rn(pcx, __fmul_rn(0.5f, pw)), 1.0f);
    float oy2 = __fsub_rn(__fadd_rn(pcy, __fmul_rn(0.5f, ph)), 1.0f);
    float4 o;
    o.x = fminf(fmaxf(ox1, 0.0f), wmax);
    o.y = fminf(fmaxf(oy1, 0.0f), hmax);
    o.z = fminf(fmaxf(ox2, 0.0f), wmax);
    o.w = fminf(fmaxf(oy2, 0.0f), hmax);
    return o;
}

__device__ __forceinline__ float iou_legacy(float ax1, float ay1, float ax2, float ay2,
                                            float bx1, float by1, float bx2, float by2) {
    float aw = __fadd_rn(__fsub_rn(ax2, ax1), 1.0f);
    float ah = __fadd_rn(__fsub_rn(ay2, ay1), 1.0f);
    float areaA = __fmul_rn(aw, ah);
    float bw = __fadd_rn(__fsub_rn(bx2, bx1), 1.0f);
    float bh = __fadd_rn(__fsub_rn(by2, by1), 1.0f);
    float areaB = __fmul_rn(bw, bh);
    float ltx = fmaxf(ax1, bx1), lty = fmaxf(ay1, by1);
    float rbx = fminf(ax2, bx2), rby = fminf(ay2, by2);
    float wx = fmaxf(__fadd_rn(__fsub_rn(rbx, ltx), 1.0f), 0.0f);
    float wy = fmaxf(__fadd_rn(__fsub_rn(rby, lty), 1.0f), 0.0f);
    float inter = __fmul_rn(wx, wy);
    float denom = __fsub_rn(__fadd_rn(areaA, areaB), inter);
    return inter / denom;
}

// monotone coarse bin of a positive float score (positive IEEE bits are order-preserving)
__device__ __forceinline__ int bin_of(float s) {
    int idx = (int)(__float_as_uint(s) >> 16) - 0x3D00;   // scores in (0.05,1] -> [76,640]
    return idx < 0 ? 0 : (idx > NBINS - 1 ? NBINS - 1 : idx);
}

__device__ __forceinline__ unsigned long long key_of(float s, unsigned f) {
    // (score desc, flat asc) as one monotone u64; valid keys nonzero (score > 0.05)
    return ((unsigned long long)__float_as_uint(s) << 32) | (unsigned long long)(~f);
}
__device__ __forceinline__ float key_score(unsigned long long k) {
    return __uint_as_float((unsigned)(k >> 32));
}
__device__ __forceinline__ int key_flat(unsigned long long k) {
    return (int)(~(unsigned)k);
}

// device-scope (sc1) coherent accesses. R7 lesson: NEVER spin-poll these (remote plain
// stores don't invalidate local L2). Safe here: all cross-block SIGNALING is atomic-RMW;
// sc1 data reads happen once, after the RMW handoff, and hold deterministic values
// (bit-identical across replays), so even a stale hit returns correct bits.
__device__ __forceinline__ void dev_store_u64(unsigned long long* p, unsigned long long v) {
    __hip_atomic_store(p, v, __ATOMIC_RELAXED, __HIP_MEMORY_SCOPE_AGENT);
}
__device__ __forceinline__ unsigned long long dev_load_u64(const unsigned long long* p) {
    return __hip_atomic_load(p, __ATOMIC_RELAXED, __HIP_MEMORY_SCOPE_AGENT);
}
__device__ __forceinline__ void dev_store_i32(int* p, int v) {
    __hip_atomic_store(p, v, __ATOMIC_RELAXED, __HIP_MEMORY_SCOPE_AGENT);
}

// upper-bound search: returns c with koff[c] <= g < koff[c+1]
__device__ __forceinline__ int find_class(const int* koff, int g) {
    int lo = 0, hi = NBLK_CLS;
    while (hi - lo > 1) { int mid = (lo + hi) >> 1; if (g >= koff[mid]) lo = mid; else hi = mid; }
    return lo;
}

// ---------- Kernel A: per-row softmax stats (1000-way parallel) + zero `done` ----------

__global__ __launch_bounds__(64) void k_softmax_stats(const float* __restrict__ logits,
                                                      float* __restrict__ rowmax,
                                                      float* __restrict__ rowsum,
                                                      int* __restrict__ done) {
    int r = blockIdx.x;
    int l = threadIdx.x;
    if (r == 0 && l == 0) *done = 0;   // plain store; kernel-boundary visibility (R1-R5 proven)
    float v1 = logits[r * NCLS + l];
    float v2 = (l < NCLS - 64) ? logits[r * NCLS + 64 + l] : -INFINITY;
    float m = fmaxf(v1, v2);
    #pragma unroll
    for (int off = 32; off; off >>= 1) m = fmaxf(m, __shfl_xor(m, off));
    float s = expf(__fsub_rn(v1, m));
    if (l < NCLS - 64) s = __fadd_rn(s, expf(__fsub_rn(v2, m)));
    #pragma unroll
    for (int off = 32; off; off >>= 1) s = __fadd_rn(s, __shfl_xor(s, off));
    if (l == 0) { rowmax[r] = m; rowsum[r] = s; }
}

// ---------- Kernel B: 80 class blocks; last-finishing block (RMW) runs selection ----------

__global__ __launch_bounds__(256) void k_nms_select(const float* __restrict__ logits,
                                                    const float* __restrict__ reg,
                                                    const float* __restrict__ prop,
                                                    const float* __restrict__ rowmax,
                                                    const float* __restrict__ rowsum,
                                                    const int* __restrict__ piw,
                                                    const int* __restrict__ pih,
                                                    unsigned long long* __restrict__ klist,
                                                    int* __restrict__ kcount,
                                                    int* __restrict__ done,
                                                    float* __restrict__ out) {
    // class-phase LDS
    __shared__ float us[MAXC];  __shared__ int uidx[MAXC];
    __shared__ float ss[MAXC];  __shared__ int sidx[MAXC];
    __shared__ float bx4[MAXC][4];
    __shared__ int   supp[MAXC];
    __shared__ int   cnt, sh_last;
    // selector-phase LDS
    __shared__ int   koff[NBLK_CLS + 1];
    __shared__ int   cs[256];
    __shared__ int   hist_s[NBINS];
    __shared__ unsigned long long ck[CK_CAP + 4];
    __shared__ unsigned long long cks[SURV_CAP + 4];
    __shared__ float sel_s[DETS]; __shared__ int sel_f[DETS];
    __shared__ int   sh_cut, sh_mcnt;

    const int cidx = blockIdx.x;       // 0..79
    const int ccol = cidx + 1;         // skip background class 0
    const int t    = threadIdx.x;
    const int lane = t & 63;
    const int wv   = t >> 6;
    const float wmax = (float)(*piw - 1);
    const float hmax = (float)(*pih - 1);

    if (t == 0) cnt = 0;
    __syncthreads();

    // ---- Phase 1: valid candidates (score > thresh), unsorted compaction into LDS ----
    for (int r = t; r < R_ROWS; r += 256) {
        float z = logits[r * NCLS + ccol];
        float s = expf(__fsub_rn(z, rowmax[r])) / rowsum[r];
        if (s > SCORE_T) {
            int p = atomicAdd(&cnt, 1);
            us[p] = s; uidx[p] = r;
        }
    }
    __syncthreads();
    const int M = cnt;

    // ---- Phase 2a: exact rank sort (score desc, row asc) ----
    for (int i = t; i < M; i += 256) {
        float si = us[i]; int ri = uidx[i];
        int rank = 0;
        for (int j = 0; j < M; j++) {
            float sj = us[j]; int rj = uidx[j];
            rank += (sj > si) || (sj == si && rj < ri);
        }
        ss[rank] = si; sidx[rank] = ri;
    }
    __syncthreads();
    // ---- Phase 2b: decode + clip ----
    for (int i = t; i < M; i += 256) {
        float4 b = decode_clip(prop, reg, sidx[i], ccol, wmax, hmax);
        bx4[i][0] = b.x; bx4[i][1] = b.y; bx4[i][2] = b.z; bx4[i][3] = b.w;
        supp[i] = 0;
    }
    __syncthreads();

    // ---- Phase 3+4: NMS + write kept keys to fixed per-class slots (zero contention) ----
    if (M <= 64) {
        // wave-ballot NMS on wave 0 (R7/R8-validated): no barriers, no LDS traffic
        if (wv == 0) {
            const bool valid = lane < M;
            float b0 = 0, b1 = 0, b2 = 0, b3 = 0, sc = 0; int ri = 0;
            if (valid) { b0 = bx4[lane][0]; b1 = bx4[lane][1]; b2 = bx4[lane][2]; b3 = bx4[lane][3];
                         sc = ss[lane]; ri = sidx[lane]; }
            unsigned long long suppm = 0;
            for (int i = 0; i < M; ++i) {
                if ((suppm >> i) & 1ULL) continue;          // wave-uniform
                float ax1 = __shfl(b0, i), ay1 = __shfl(b1, i);
                float ax2 = __shfl(b2, i), ay2 = __shfl(b3, i);
                bool kill = valid && (lane > i) &&
                            (iou_legacy(ax1, ay1, ax2, ay2, b0, b1, b2, b3) > NMS_T);
                suppm |= __ballot(kill);
            }
            unsigned long long keepm = ~suppm;
            if (M < 64) keepm &= (1ULL << M) - 1ULL;
            if (valid && ((keepm >> lane) & 1ULL)) {
                int pos = __popcll(keepm & ((1ULL << lane) - 1ULL));
                dev_store_u64(&klist[(size_t)cidx * SLOTS + pos],
                              key_of(sc, (unsigned)(cidx * R_ROWS + ri)));
            }
            if (lane == 0) dev_store_i32(&kcount[cidx], __popcll(keepm));
        }
    } else {
        // fallback: sequential-i LDS NMS (block-uniform branch, barriers legal)
        for (int i = 0; i < M; i++) {
            if (!supp[i]) {
                float ax1 = bx4[i][0], ay1 = bx4[i][1], ax2 = bx4[i][2], ay2 = bx4[i][3];
                for (int j = i + 1 + t; j < M; j += 256) {
                    if (!supp[j]) {
                        float v = iou_legacy(ax1, ay1, ax2, ay2,
                                             bx4[j][0], bx4[j][1], bx4[j][2], bx4[j][3]);
                        if (v > NMS_T) supp[j] = 1;
                    }
                }
            }
            __syncthreads();
        }
        for (int i = t; i < M; i += 256) {
            if (!supp[i]) {
                int pos = 0;
                for (int j = 0; j < i; ++j) pos += !supp[j];
                dev_store_u64(&klist[(size_t)cidx * SLOTS + pos],
                              key_of(ss[i], (unsigned)(cidx * R_ROWS + sidx[i])));
            }
        }
        if (t == 0) {
            int kc = 0;
            for (int i = 0; i < M; ++i) kc += !supp[i];
            dev_store_i32(&kcount[cidx], kc);
        }
    }

    // ---- last-block handoff: RMW only (R7 lesson) ----
    __syncthreads();   // drains vmcnt(0): all sc1 stores at coherence point
    if (t == 0) sh_last = (atomicAdd(done, 1) == NBLK_CLS - 1) ? 1 : 0;
    __syncthreads();
    if (!sh_last) return;

    // ================= selector (exactly one block: the last to finish) =================
    // per-class counts via RMW-reads (always fresh at coherence point)
    if (t < NBLK_CLS) cs[t] = atomicAdd(&kcount[t], 0);
    for (int b = t; b < NBINS; b += 256) hist_s[b] = 0;
    __syncthreads();
    if (t == 0) {
        int acc = 0;
        for (int c = 0; c < NBLK_CLS; ++c) { koff[c] = acc; acc += cs[c]; }
        koff[NBLK_CLS] = acc;
        sh_cut = 0; sh_mcnt = 0;
    }
    __syncthreads();
    const int K = koff[NBLK_CLS];
    const int target = (K < DETS) ? K : DETS;

    if (K <= CK_CAP) {
        // single sc1 sweep: keys -> LDS + LDS histogram
        for (int g = t; g < K; g += 256) {
            int c = find_class(koff, g);
            unsigned long long k = dev_load_u64(&klist[(size_t)c * SLOTS + (g - koff[c])]);
            ck[g] = k;
            atomicAdd(&hist_s[bin_of(key_score(k))], 1);
        }
        __syncthreads();

        // suffix scan of 1024 bins: S[b] = #keys with bin >= b
        int v0 = hist_s[4 * t], v1 = hist_s[4 * t + 1], v2 = hist_s[4 * t + 2], v3 = hist_s[4 * t + 3];
        int s3 = v3, s2 = v2 + s3, s1 = v1 + s2, s0 = v0 + s1;
        cs[t] = s0;
        __syncthreads();
        for (int off = 1; off < 256; off <<= 1) {
            int x = cs[t] + ((t + off < 256) ? cs[t + off] : 0);
            __syncthreads();
            cs[t] = x;
            __syncthreads();
        }
        int tail = (t < 255) ? cs[t + 1] : 0;
        int S0 = s0 + tail, S1 = s1 + tail, S2 = s2 + tail, S3 = s3 + tail;
        if (target > 0) {
            int best = -1;
            if      (S3 >= target) best = 4 * t + 3;
            else if (S2 >= target) best = 4 * t + 2;
            else if (S1 >= target) best = 4 * t + 1;
            else if (S0 >= target) best = 4 * t;
            if (best >= 0) atomicMax(&sh_cut, best);
        }
        __syncthreads();
        const int cut = sh_cut;   // survivors (bin >= cut) ⊇ top-target

        // compact survivors in-LDS
        for (int g = t; g < K; g += 256) {
            unsigned long long k = ck[g];
            if (bin_of(key_score(k)) >= cut) {
                int p = atomicAdd(&sh_mcnt, 1);
                if (p < SURV_CAP) cks[p] = k;
            }
        }
        __syncthreads();
        const int Mc = sh_mcnt;

        if (Mc <= SURV_CAP) {
            // exact rank among survivors (== global ranks; bijective -> direct scatter)
            int Mp = (Mc + 3) & ~3;
            if (t < Mp - Mc) cks[Mc + t] = 0;   // pad: key 0 never outranks a real key
            __syncthreads();
            for (int i = t; i < Mc; i += 256) {
                unsigned long long ki = cks[i];
                int r = 0;
                for (int j = 0; j < Mp; j += 4)
                    r += (int)(cks[j] > ki) + (int)(cks[j + 1] > ki)
                       + (int)(cks[j + 2] > ki) + (int)(cks[j + 3] > ki);
                if (r < DETS) {
                    sel_s[r] = key_score(ki);
                    sel_f[r] = key_flat(ki);
                }
            }
        } else {
            // degenerate tie flood: rank survivors against full ck (LDS, slower, correct)
            int Kp = (K + 3) & ~3;
            if (t < Kp - K) ck[K + t] = 0;
            __syncthreads();
            for (int g = t; g < K; g += 256) {
                unsigned long long ki = ck[g];
                if (bin_of(key_score(ki)) < cut) continue;
                int r = 0;
                for (int j = 0; j < Kp; j += 4)
                    r += (int)(ck[j] > ki) + (int)(ck[j + 1] > ki)
                       + (int)(ck[j + 2] > ki) + (int)(ck[j + 3] > ki);
                if (r < DETS) {
                    sel_s[r] = key_score(ki);
                    sel_f[r] = key_flat(ki);
                }
            }
        }
    } else {
        // K > CK_CAP (not reachable in practice): exact rank via global sc1 sweeps
        for (int g = t; g < K; g += 256) {
            int c = find_class(koff, g);
            unsigned long long ki = dev_load_u64(&klist[(size_t)c * SLOTS + (g - koff[c])]);
            int r = 0;
            for (int g2 = 0; g2 < K; ++g2) {
                int c2 = find_class(koff, g2);
                r += (int)(dev_load_u64(&klist[(size_t)c2 * SLOTS + (g2 - koff[c2])]) > ki);
            }
            if (r < DETS) {
                sel_s[r] = key_score(ki);
                sel_f[r] = key_flat(ki);
            }
        }
    }
    __syncthreads();

    // tail-fill (only when K < 100: then cut==0, Mc==K, cks holds ALL kept keys)
    if (t == 0 && target < DETS) {
        int n = target, f = 0;
        while (n < DETS) {
            bool used = false;
            for (int q = 0; q < target; q++) if (key_flat(cks[q]) == f) { used = true; break; }
            if (!used) { sel_s[n] = NEG_S; sel_f[n] = f; n++; }
            f++;
        }
    }
    __syncthreads();

    // decode + write 600 outputs
    if (t < DETS) {
        int f = sel_f[t];
        int c2 = f / R_ROWS;
        int r  = f % R_ROWS;
        float4 b = decode_clip(prop, reg, r, c2 + 1, wmax, hmax);
        out[t] = sel_s[t];
        out[DETS + 4 * t + 0] = b.x;
        out[DETS + 4 * t + 1] = b.y;
        out[DETS + 4 * t + 2] = b.z;
        out[DETS + 4 * t + 3] = b.w;
        out[DETS * 5 + t] = (float)(c2 + 1);
    }
}

// ---------- host launcher ----------

extern "C" void kernel_launch(void* const* d_in, const int* in_sizes, int n_in,
                              void* d_out, int out_size, void* d_ws, size_t ws_size,
                              hipStream_t stream) {
    (void)in_sizes; (void)n_in; (void)out_size; (void)ws_size;
    const float* logits = (const float*)d_in[0];
    const float* reg    = (const float*)d_in[1];
    const float* prop   = (const float*)d_in[2];
    const int*   piw    = (const int*)d_in[3];
    const int*   pih    = (const int*)d_in[4];
    float* out = (float*)d_out;

    // workspace (bytes): done@0, kcount[80]@64, rowmax[1000]@1024, rowsum[1000]@5120,
    // klist[80*1000 u64]@12288. Only `done` needs zeroing (kernel A does it);
    // kcount/klist are fully overwritten-before-read each call (deterministic values).
    char* ws = (char*)d_ws;
    int*   done    = (int*)(ws);
    int*   kcount  = (int*)(ws + 64);
    float* rowmax  = (float*)(ws + 1024);
    float* rowsum  = (float*)(ws + 5120);
    unsigned long long* klist = (unsigned long long*)(ws + 12288);

    k_softmax_stats<<<dim3(R_ROWS), dim3(64), 0, stream>>>(logits, rowmax, rowsum, done);
    k_nms_select<<<dim3(NBLK_CLS), dim3(256), 0, stream>>>(logits, reg, prop, rowmax, rowsum,
                                                           piw, pih, klist, kcount, done, out);
}